// Round 1
// baseline (95.718 us; speedup 1.0000x reference)
//
#include <hip/hip_runtime.h>

// Problem constants (from reference)
#define OUT_H 7
#define OUT_W 7
#define NBINS 49
#define SCALE 0.0625f
#define CCH 256
#define FH 100
#define FW 100
#define FS (FH * FW)

// ---------------------------------------------------------------------------
// Kernel 1: NCHW -> NHWC transpose of feat into workspace.
// Treat per-batch as 2D transpose of (C, S) -> (S, C), S = H*W.
// ---------------------------------------------------------------------------
__global__ __launch_bounds__(256) void transpose_kernel(const float* __restrict__ in,
                                                        float* __restrict__ out) {
    __shared__ float tile[32][33];  // +1 pad: conflict-free transpose
    const int n  = blockIdx.z;
    const int s0 = blockIdx.x * 32;  // spatial tile origin
    const int c0 = blockIdx.y * 32;  // channel tile origin
    const int tx = threadIdx.x, ty = threadIdx.y;

    for (int k = ty; k < 32; k += 8) {
        int c = c0 + k, s = s0 + tx;
        if (s < FS) tile[k][tx] = in[((size_t)n * CCH + c) * FS + s];
    }
    __syncthreads();
    for (int k = ty; k < 32; k += 8) {
        int s = s0 + k, c = c0 + tx;
        if (s < FS) out[((size_t)n * FS + s) * CCH + c] = tile[tx][k];
    }
}

// ---------------------------------------------------------------------------
// Kernel 2: RoIAlign. One block per roi, 256 threads = 256 channels.
// Coordinates/weights are wave-uniform; per-lane work is the 16 bilinear taps.
// Results staged in LDS so the final global write is fully coalesced over the
// roi's contiguous (C*49)-float output region.
// TRANSPOSED=true reads NHWC from workspace; false reads NCHW directly.
// ---------------------------------------------------------------------------
template <bool TRANSPOSED>
__global__ __launch_bounds__(256) void roi_align_kernel(const float* __restrict__ feat,
                                                        const float* __restrict__ rois,
                                                        float* __restrict__ out) {
    const int r = blockIdx.x;
    const int c = threadIdx.x;

    __shared__ float tile[CCH * NBINS];  // 50176 B

    const float* roi = rois + (size_t)r * 5;
    const int   b  = (int)roi[0];
    const float sx = roi[1] * SCALE - 0.5f;
    const float sy = roi[2] * SCALE - 0.5f;
    const float ex = roi[3] * SCALE - 0.5f;
    const float ey = roi[4] * SCALE - 0.5f;
    const float bin_h = (ey - sy) / (float)OUT_H;
    const float bin_w = (ex - sx) / (float)OUT_W;

    const float* fb;
    if (TRANSPOSED) {
        fb = feat + (size_t)b * FS * CCH;          // NHWC: [(y*W+x)*C + c]
    } else {
        fb = feat + ((size_t)b * CCH + c) * FS;    // NCHW: [y*W + x]
    }

    for (int ph = 0; ph < OUT_H; ++ph) {
        for (int pw = 0; pw < OUT_W; ++pw) {
            float acc = 0.0f;
#pragma unroll
            for (int iy = 0; iy < 2; ++iy) {
#pragma unroll
                for (int ix = 0; ix < 2; ++ix) {
                    float y = sy + ((float)ph + ((float)iy + 0.5f) * 0.5f) * bin_h;
                    float x = sx + ((float)pw + ((float)ix + 0.5f) * 0.5f) * bin_w;
                    bool valid = (y >= -1.0f) && (y <= (float)FH) &&
                                 (x >= -1.0f) && (x <= (float)FW);
                    y = fminf(fmaxf(y, 0.0f), (float)(FH - 1));
                    x = fminf(fmaxf(x, 0.0f), (float)(FW - 1));
                    int ylo = (int)floorf(y);
                    int xlo = (int)floorf(x);
                    int yhi = min(ylo + 1, FH - 1);
                    int xhi = min(xlo + 1, FW - 1);
                    float ly = y - (float)ylo, lx = x - (float)xlo;
                    float hy = 1.0f - ly, hx = 1.0f - lx;
                    if (valid) {  // wave-uniform branch, no divergence
                        float f00, f01, f10, f11;
                        if (TRANSPOSED) {
                            f00 = fb[((size_t)(ylo * FW + xlo)) * CCH + c];
                            f01 = fb[((size_t)(ylo * FW + xhi)) * CCH + c];
                            f10 = fb[((size_t)(yhi * FW + xlo)) * CCH + c];
                            f11 = fb[((size_t)(yhi * FW + xhi)) * CCH + c];
                        } else {
                            f00 = fb[ylo * FW + xlo];
                            f01 = fb[ylo * FW + xhi];
                            f10 = fb[yhi * FW + xlo];
                            f11 = fb[yhi * FW + xhi];
                        }
                        acc += hy * hx * f00 + hy * lx * f01 +
                               ly * hx * f10 + ly * lx * f11;
                    }
                }
            }
            tile[c * NBINS + ph * OUT_W + pw] = acc * 0.25f;
        }
    }

    __syncthreads();
    // Coalesced write of this roi's contiguous C*49 output floats.
    float* outr = out + (size_t)r * CCH * NBINS;
    for (int i = c; i < CCH * NBINS; i += 256) outr[i] = tile[i];
}

extern "C" void kernel_launch(void* const* d_in, const int* in_sizes, int n_in,
                              void* d_out, int out_size, void* d_ws, size_t ws_size,
                              hipStream_t stream) {
    const float* feat = (const float*)d_in[0];
    const float* rois = (const float*)d_in[1];
    float* out = (float*)d_out;

    const int R = in_sizes[1] / 5;
    const int N = in_sizes[0] / (CCH * FS);

    const size_t need = (size_t)N * FS * CCH * sizeof(float);
    if (ws_size >= need) {
        dim3 tb(32, 8);
        dim3 tg((FS + 31) / 32, CCH / 32, N);
        transpose_kernel<<<tg, tb, 0, stream>>>(feat, (float*)d_ws);
        roi_align_kernel<true><<<R, 256, 0, stream>>>((const float*)d_ws, rois, out);
    } else {
        roi_align_kernel<false><<<R, 256, 0, stream>>>(feat, rois, out);
    }
}

// Round 2
// 38.449 us; speedup vs baseline: 2.4895x; 2.4895x over previous
//
#include <hip/hip_runtime.h>

// Problem constants (from reference)
#define OUT_H 7
#define OUT_W 7
#define NBINS 49
#define SCALE 0.0625f
#define CCH 256
#define FH 100
#define FW 100
#define FS (FH * FW)

// ---------------------------------------------------------------------------
// Kernel 1: NCHW -> NHWC transpose, float4 on both global phases.
// Tile: 32 channels x 128 spatial, 16.5 KB LDS.
// ---------------------------------------------------------------------------
#define TS_S 128
#define TS_C 32

__global__ __launch_bounds__(256) void transpose_kernel(const float* __restrict__ in,
                                                        float* __restrict__ out) {
    __shared__ float tile[TS_C][TS_S + 4];  // row stride 132 floats: 16B-aligned, banks offset by 4
    const int n  = blockIdx.z;
    const int s0 = blockIdx.x * TS_S;
    const int c0 = blockIdx.y * TS_C;
    const int tid = threadIdx.x;

    // Read phase: 32 rows x 32 float4 per row; lane = s-direction (coalesced 512B/wave)
    const int cr = tid >> 5;         // 0..7
    const int s4 = (tid & 31) * 4;   // 0..124
#pragma unroll
    for (int it = 0; it < 4; ++it) {
        const int c = c0 + cr + it * 8;
        const int s = s0 + s4;
        float4 v = {0.f, 0.f, 0.f, 0.f};
        if (s < FS) v = *(const float4*)&in[((size_t)n * CCH + c) * FS + s];
        *(float4*)&tile[cr + it * 8][s4] = v;
    }
    __syncthreads();
    // Write phase: float4 over channels (coalesced 512B/wave on NHWC side)
    const int c4  = (tid & 7) * 4;   // 0,4,..28
    const int sr0 = tid >> 3;        // 0..31
#pragma unroll
    for (int it = 0; it < 4; ++it) {
        const int sr = sr0 + it * 32;
        const int s  = s0 + sr;
        if (s < FS) {
            float4 v = { tile[c4][sr], tile[c4 + 1][sr], tile[c4 + 2][sr], tile[c4 + 3][sr] };
            *(float4*)&out[((size_t)n * FS + s) * CCH + c0 + c4] = v;
        }
    }
}

// ---------------------------------------------------------------------------
// Kernel 2: RoIAlign on NHWC. Block = (roi, 64-channel quarter), 256 threads.
// Thread = (channel-group cg: 4 channels via float4) x (bin slot: bins slot::16).
// 16 independent float4 loads per bin -> deep memory-level parallelism.
// Output staged in 12.5KB LDS, then one contiguous coalesced 12.5KB write.
// ---------------------------------------------------------------------------
__global__ __launch_bounds__(256, 4) void roi_align_nhwc(const float* __restrict__ feat,
                                                         const float* __restrict__ rois,
                                                         float* __restrict__ out) {
    const int r   = blockIdx.y;
    const int c0  = blockIdx.x * 64;
    const int tid = threadIdx.x;
    const int cg   = tid & 15;  // channel group (4 channels)
    const int slot = tid >> 4;  // bin slot 0..15

    __shared__ float tile[64 * NBINS];  // 12544 B

    const float* roi = rois + (size_t)r * 5;
    const int   b  = (int)roi[0];
    const float sx = roi[1] * SCALE - 0.5f;
    const float sy = roi[2] * SCALE - 0.5f;
    const float ex = roi[3] * SCALE - 0.5f;
    const float ey = roi[4] * SCALE - 0.5f;
    const float bin_h = (ey - sy) * (1.0f / (float)OUT_H);
    const float bin_w = (ex - sx) * (1.0f / (float)OUT_W);

    const float* fb = feat + ((size_t)b * FS) * CCH + (c0 + cg * 4);

    for (int bin = slot; bin < NBINS; bin += 16) {
        const int ph = bin / 7;
        const int pw = bin - ph * 7;
        float ax = 0.f, ay = 0.f, az = 0.f, aw = 0.f;
#pragma unroll
        for (int iy = 0; iy < 2; ++iy) {
            float y = sy + ((float)ph + 0.25f + 0.5f * (float)iy) * bin_h;
            const bool vy = (y >= -1.0f) && (y <= (float)FH);
            y = fminf(fmaxf(y, 0.0f), (float)(FH - 1));
            const int ylo = (int)y;  // y >= 0, trunc == floor
            const int yhi = min(ylo + 1, FH - 1);
            const float ly = y - (float)ylo, hy = 1.0f - ly;
#pragma unroll
            for (int ix = 0; ix < 2; ++ix) {
                float x = sx + ((float)pw + 0.25f + 0.5f * (float)ix) * bin_w;
                const bool vx = (x >= -1.0f) && (x <= (float)FW);
                x = fminf(fmaxf(x, 0.0f), (float)(FW - 1));
                const int xlo = (int)x;
                const int xhi = min(xlo + 1, FW - 1);
                const float lx = x - (float)xlo, hx = 1.0f - lx;
                if (vy && vx) {
                    const float4 f00 = *(const float4*)&fb[(size_t)(ylo * FW + xlo) * CCH];
                    const float4 f01 = *(const float4*)&fb[(size_t)(ylo * FW + xhi) * CCH];
                    const float4 f10 = *(const float4*)&fb[(size_t)(yhi * FW + xlo) * CCH];
                    const float4 f11 = *(const float4*)&fb[(size_t)(yhi * FW + xhi) * CCH];
                    const float w00 = hy * hx, w01 = hy * lx, w10 = ly * hx, w11 = ly * lx;
                    ax += w00 * f00.x + w01 * f01.x + w10 * f10.x + w11 * f11.x;
                    ay += w00 * f00.y + w01 * f01.y + w10 * f10.y + w11 * f11.y;
                    az += w00 * f00.z + w01 * f01.z + w10 * f10.z + w11 * f11.z;
                    aw += w00 * f00.w + w01 * f01.w + w10 * f10.w + w11 * f11.w;
                }
            }
        }
        const int chb = cg * 4;
        tile[(chb + 0) * NBINS + bin] = ax * 0.25f;
        tile[(chb + 1) * NBINS + bin] = ay * 0.25f;
        tile[(chb + 2) * NBINS + bin] = az * 0.25f;
        tile[(chb + 3) * NBINS + bin] = aw * 0.25f;
    }

    __syncthreads();
    // Contiguous, coalesced 64*49-float write for this (roi, channel-quarter).
    float* outr = out + ((size_t)r * CCH + c0) * NBINS;
    for (int i = tid; i < 64 * NBINS; i += 256) outr[i] = tile[i];
}

// ---------------------------------------------------------------------------
// Fallback: direct NCHW kernel (used only if workspace is too small).
// ---------------------------------------------------------------------------
__global__ __launch_bounds__(256) void roi_align_nchw(const float* __restrict__ feat,
                                                      const float* __restrict__ rois,
                                                      float* __restrict__ out) {
    const int r = blockIdx.x;
    const int c = threadIdx.x;
    __shared__ float tile[CCH * NBINS];

    const float* roi = rois + (size_t)r * 5;
    const int   b  = (int)roi[0];
    const float sx = roi[1] * SCALE - 0.5f;
    const float sy = roi[2] * SCALE - 0.5f;
    const float ex = roi[3] * SCALE - 0.5f;
    const float ey = roi[4] * SCALE - 0.5f;
    const float bin_h = (ey - sy) / (float)OUT_H;
    const float bin_w = (ex - sx) / (float)OUT_W;
    const float* fb = feat + ((size_t)b * CCH + c) * FS;

    for (int bin = 0; bin < NBINS; ++bin) {
        const int ph = bin / 7, pw = bin - ph * 7;
        float acc = 0.0f;
#pragma unroll
        for (int iy = 0; iy < 2; ++iy) {
#pragma unroll
            for (int ix = 0; ix < 2; ++ix) {
                float y = sy + ((float)ph + 0.25f + 0.5f * iy) * bin_h;
                float x = sx + ((float)pw + 0.25f + 0.5f * ix) * bin_w;
                bool valid = (y >= -1.0f) && (y <= (float)FH) && (x >= -1.0f) && (x <= (float)FW);
                y = fminf(fmaxf(y, 0.0f), (float)(FH - 1));
                x = fminf(fmaxf(x, 0.0f), (float)(FW - 1));
                int ylo = (int)y, xlo = (int)x;
                int yhi = min(ylo + 1, FH - 1), xhi = min(xlo + 1, FW - 1);
                float ly = y - ylo, lx = x - xlo, hy = 1.f - ly, hx = 1.f - lx;
                if (valid)
                    acc += hy * hx * fb[ylo * FW + xlo] + hy * lx * fb[ylo * FW + xhi] +
                           ly * hx * fb[yhi * FW + xlo] + ly * lx * fb[yhi * FW + xhi];
            }
        }
        tile[c * NBINS + bin] = acc * 0.25f;
    }
    __syncthreads();
    float* outr = out + (size_t)r * CCH * NBINS;
    for (int i = c; i < CCH * NBINS; i += 256) outr[i] = tile[i];
}

extern "C" void kernel_launch(void* const* d_in, const int* in_sizes, int n_in,
                              void* d_out, int out_size, void* d_ws, size_t ws_size,
                              hipStream_t stream) {
    const float* feat = (const float*)d_in[0];
    const float* rois = (const float*)d_in[1];
    float* out = (float*)d_out;

    const int R = in_sizes[1] / 5;
    const int N = in_sizes[0] / (CCH * FS);

    const size_t need = (size_t)N * FS * CCH * sizeof(float);
    if (ws_size >= need) {
        dim3 tb(256);
        dim3 tg((FS + TS_S - 1) / TS_S, CCH / TS_C, N);
        transpose_kernel<<<tg, tb, 0, stream>>>(feat, (float*)d_ws);
        dim3 rg(CCH / 64, R);
        roi_align_nhwc<<<rg, 256, 0, stream>>>((const float*)d_ws, rois, out);
    } else {
        roi_align_nchw<<<R, 256, 0, stream>>>(feat, rois, out);
    }
}

// Round 3
// 36.743 us; speedup vs baseline: 2.6050x; 1.0464x over previous
//
#include <hip/hip_runtime.h>

// Problem constants (from reference)
#define OUT_H 7
#define OUT_W 7
#define NBINS 49
#define SCALE 0.0625f
#define CCH 256
#define FH 100
#define FW 100
#define FS (FH * FW)

// ---------------------------------------------------------------------------
// Kernel 1: NCHW -> NHWC transpose, float4 on both global phases.
// Tile: 32 channels x 128 spatial, 16.5 KB LDS.
// ---------------------------------------------------------------------------
#define TS_S 128
#define TS_C 32

__global__ __launch_bounds__(256) void transpose_kernel(const float* __restrict__ in,
                                                        float* __restrict__ out) {
    __shared__ float tile[TS_C][TS_S + 4];  // row stride 132 floats: 16B-aligned, banks offset by 4
    const int n  = blockIdx.z;
    const int s0 = blockIdx.x * TS_S;
    const int c0 = blockIdx.y * TS_C;
    const int tid = threadIdx.x;

    // Read phase: lane = s-direction (coalesced 512B/wave)
    const int cr = tid >> 5;         // 0..7
    const int s4 = (tid & 31) * 4;   // 0..124
#pragma unroll
    for (int it = 0; it < 4; ++it) {
        const int c = c0 + cr + it * 8;
        const int s = s0 + s4;
        float4 v = {0.f, 0.f, 0.f, 0.f};
        if (s < FS) v = *(const float4*)&in[((size_t)n * CCH + c) * FS + s];
        *(float4*)&tile[cr + it * 8][s4] = v;
    }
    __syncthreads();
    // Write phase: float4 over channels (coalesced on NHWC side)
    const int c4  = (tid & 7) * 4;   // 0,4,..28
    const int sr0 = tid >> 3;        // 0..31
#pragma unroll
    for (int it = 0; it < 4; ++it) {
        const int sr = sr0 + it * 32;
        const int s  = s0 + sr;
        if (s < FS) {
            float4 v = { tile[c4][sr], tile[c4 + 1][sr], tile[c4 + 2][sr], tile[c4 + 3][sr] };
            *(float4*)&out[((size_t)n * FS + s) * CCH + c0 + c4] = v;
        }
    }
}

// ---------------------------------------------------------------------------
// Kernel 2: RoIAlign on NHWC. 1D grid of R*8 blocks; slice = bid & 7 so each
// channel-slice (32 ch) pins to one XCD under round-robin dispatch: per-XCD
// L2 working set = FS*32ch*4B*2batch = 2.56 MB < 4 MB -> feat fetched ~once.
// Thread = (channel-group cg: 4 ch via float4) x (bin slot: bins slot::32).
// ---------------------------------------------------------------------------
__global__ __launch_bounds__(256, 4) void roi_align_nhwc(const float* __restrict__ feat,
                                                         const float* __restrict__ rois,
                                                         float* __restrict__ out) {
    const int bid   = blockIdx.x;
    const int slice = bid & 7;         // -> XCD (slice) under round-robin dispatch
    const int r     = bid >> 3;
    const int c0    = slice * 32;
    const int tid   = threadIdx.x;
    const int cg    = tid & 7;         // channel group (4 channels)
    const int slot  = tid >> 3;        // bin slot 0..31

    __shared__ float tile[32 * NBINS];  // 6272 B

    const float* roi = rois + (size_t)r * 5;
    const int   b  = (int)roi[0];
    const float sx = roi[1] * SCALE - 0.5f;
    const float sy = roi[2] * SCALE - 0.5f;
    const float ex = roi[3] * SCALE - 0.5f;
    const float ey = roi[4] * SCALE - 0.5f;
    const float bin_h = (ey - sy) * (1.0f / (float)OUT_H);
    const float bin_w = (ex - sx) * (1.0f / (float)OUT_W);

    const float* fb = feat + ((size_t)b * FS) * CCH + (c0 + cg * 4);

    for (int bin = slot; bin < NBINS; bin += 32) {
        const int ph = bin / 7;
        const int pw = bin - ph * 7;
        float ax = 0.f, ay = 0.f, az = 0.f, aw = 0.f;
#pragma unroll
        for (int iy = 0; iy < 2; ++iy) {
            float y = sy + ((float)ph + 0.25f + 0.5f * (float)iy) * bin_h;
            const bool vy = (y >= -1.0f) && (y <= (float)FH);
            y = fminf(fmaxf(y, 0.0f), (float)(FH - 1));
            const int ylo = (int)y;  // y >= 0, trunc == floor
            const int yhi = min(ylo + 1, FH - 1);
            const float ly = y - (float)ylo, hy = 1.0f - ly;
#pragma unroll
            for (int ix = 0; ix < 2; ++ix) {
                float x = sx + ((float)pw + 0.25f + 0.5f * (float)ix) * bin_w;
                const bool vx = (x >= -1.0f) && (x <= (float)FW);
                x = fminf(fmaxf(x, 0.0f), (float)(FW - 1));
                const int xlo = (int)x;
                const int xhi = min(xlo + 1, FW - 1);
                const float lx = x - (float)xlo, hx = 1.0f - lx;
                if (vy && vx) {
                    const float4 f00 = *(const float4*)&fb[(size_t)(ylo * FW + xlo) * CCH];
                    const float4 f01 = *(const float4*)&fb[(size_t)(ylo * FW + xhi) * CCH];
                    const float4 f10 = *(const float4*)&fb[(size_t)(yhi * FW + xlo) * CCH];
                    const float4 f11 = *(const float4*)&fb[(size_t)(yhi * FW + xhi) * CCH];
                    const float w00 = hy * hx, w01 = hy * lx, w10 = ly * hx, w11 = ly * lx;
                    ax += w00 * f00.x + w01 * f01.x + w10 * f10.x + w11 * f11.x;
                    ay += w00 * f00.y + w01 * f01.y + w10 * f10.y + w11 * f11.y;
                    az += w00 * f00.z + w01 * f01.z + w10 * f10.z + w11 * f11.z;
                    aw += w00 * f00.w + w01 * f01.w + w10 * f10.w + w11 * f11.w;
                }
            }
        }
        const int chb = cg * 4;
        tile[(chb + 0) * NBINS + bin] = ax * 0.25f;
        tile[(chb + 1) * NBINS + bin] = ay * 0.25f;
        tile[(chb + 2) * NBINS + bin] = az * 0.25f;
        tile[(chb + 3) * NBINS + bin] = aw * 0.25f;
    }

    __syncthreads();
    // Contiguous, coalesced 32*49-float write for this (roi, channel-slice).
    float* outr = out + ((size_t)r * CCH + c0) * NBINS;
    for (int i = tid; i < 32 * NBINS; i += 256) outr[i] = tile[i];
}

// ---------------------------------------------------------------------------
// Fallback: direct NCHW kernel (used only if workspace is too small).
// ---------------------------------------------------------------------------
__global__ __launch_bounds__(256) void roi_align_nchw(const float* __restrict__ feat,
                                                      const float* __restrict__ rois,
                                                      float* __restrict__ out) {
    const int r = blockIdx.x;
    const int c = threadIdx.x;
    __shared__ float tile[CCH * NBINS];

    const float* roi = rois + (size_t)r * 5;
    const int   b  = (int)roi[0];
    const float sx = roi[1] * SCALE - 0.5f;
    const float sy = roi[2] * SCALE - 0.5f;
    const float ex = roi[3] * SCALE - 0.5f;
    const float ey = roi[4] * SCALE - 0.5f;
    const float bin_h = (ey - sy) / (float)OUT_H;
    const float bin_w = (ex - sx) / (float)OUT_W;
    const float* fb = feat + ((size_t)b * CCH + c) * FS;

    for (int bin = 0; bin < NBINS; ++bin) {
        const int ph = bin / 7, pw = bin - ph * 7;
        float acc = 0.0f;
#pragma unroll
        for (int iy = 0; iy < 2; ++iy) {
#pragma unroll
            for (int ix = 0; ix < 2; ++ix) {
                float y = sy + ((float)ph + 0.25f + 0.5f * iy) * bin_h;
                float x = sx + ((float)pw + 0.25f + 0.5f * ix) * bin_w;
                bool valid = (y >= -1.0f) && (y <= (float)FH) && (x >= -1.0f) && (x <= (float)FW);
                y = fminf(fmaxf(y, 0.0f), (float)(FH - 1));
                x = fminf(fmaxf(x, 0.0f), (float)(FW - 1));
                int ylo = (int)y, xlo = (int)x;
                int yhi = min(ylo + 1, FH - 1), xhi = min(xlo + 1, FW - 1);
                float ly = y - ylo, lx = x - xlo, hy = 1.f - ly, hx = 1.f - lx;
                if (valid)
                    acc += hy * hx * fb[ylo * FW + xlo] + hy * lx * fb[ylo * FW + xhi] +
                           ly * hx * fb[yhi * FW + xlo] + ly * lx * fb[yhi * FW + xhi];
            }
        }
        tile[c * NBINS + bin] = acc * 0.25f;
    }
    __syncthreads();
    float* outr = out + (size_t)r * CCH * NBINS;
    for (int i = c; i < CCH * NBINS; i += 256) outr[i] = tile[i];
}

extern "C" void kernel_launch(void* const* d_in, const int* in_sizes, int n_in,
                              void* d_out, int out_size, void* d_ws, size_t ws_size,
                              hipStream_t stream) {
    const float* feat = (const float*)d_in[0];
    const float* rois = (const float*)d_in[1];
    float* out = (float*)d_out;

    const int R = in_sizes[1] / 5;
    const int N = in_sizes[0] / (CCH * FS);

    const size_t need = (size_t)N * FS * CCH * sizeof(float);
    if (ws_size >= need) {
        dim3 tb(256);
        dim3 tg((FS + TS_S - 1) / TS_S, CCH / TS_C, N);
        transpose_kernel<<<tg, tb, 0, stream>>>(feat, (float*)d_ws);
        roi_align_nhwc<<<R * 8, 256, 0, stream>>>((const float*)d_ws, rois, out);
    } else {
        roi_align_nchw<<<R, 256, 0, stream>>>(feat, rois, out);
    }
}

// Round 4
// 34.566 us; speedup vs baseline: 2.7692x; 1.0630x over previous
//
#include <hip/hip_runtime.h>

// Problem constants (from reference)
#define OUT_H 7
#define OUT_W 7
#define NBINS 49
#define SCALE 0.0625f
#define CCH 256
#define FH 100
#define FW 100
#define FS (FH * FW)

typedef _Float16 half4 __attribute__((ext_vector_type(4)));

// ---------------------------------------------------------------------------
// Kernel 1: NCHW fp32 -> NHWC fp16 transpose.
// Tile: 32 channels x 128 spatial, 16.9 KB LDS. float4 global reads,
// half4 (8B) global writes (64B contiguous per 8 lanes).
// ---------------------------------------------------------------------------
#define TS_S 128
#define TS_C 32

__global__ __launch_bounds__(256) void transpose_kernel(const float* __restrict__ in,
                                                        _Float16* __restrict__ out) {
    __shared__ float tile[TS_C][TS_S + 4];
    const int n  = blockIdx.z;
    const int s0 = blockIdx.x * TS_S;
    const int c0 = blockIdx.y * TS_C;
    const int tid = threadIdx.x;

    // Read phase: lane = s-direction (coalesced 512B/wave), float4.
    const int cr = tid >> 5;         // 0..7
    const int s4 = (tid & 31) * 4;   // 0..124
#pragma unroll
    for (int it = 0; it < 4; ++it) {
        const int c = c0 + cr + it * 8;
        const int s = s0 + s4;
        float4 v = {0.f, 0.f, 0.f, 0.f};
        if (s < FS) v = *(const float4*)&in[((size_t)n * CCH + c) * FS + s];
        *(float4*)&tile[cr + it * 8][s4] = v;
    }
    __syncthreads();
    // Write phase: half4 over channels (coalesced on NHWC side).
    const int c4  = (tid & 7) * 4;   // 0,4,..28
    const int sr0 = tid >> 3;        // 0..31
#pragma unroll
    for (int it = 0; it < 4; ++it) {
        const int sr = sr0 + it * 32;
        const int s  = s0 + sr;
        if (s < FS) {
            half4 v = { (_Float16)tile[c4 + 0][sr], (_Float16)tile[c4 + 1][sr],
                        (_Float16)tile[c4 + 2][sr], (_Float16)tile[c4 + 3][sr] };
            *(half4*)&out[((size_t)n * FS + s) * CCH + c0 + c4] = v;
        }
    }
}

// ---------------------------------------------------------------------------
// Kernel 2: RoIAlign on NHWC fp16. 1D grid of R*8 blocks; slice = bid & 7
// pins each 32-channel slice to one XCD (round-robin dispatch): per-XCD L2
// working set = FS*32ch*2B*2batch = 1.28 MB << 4 MB.
// Thread = (cg: 4 ch via half4 8B load) x (bin slot). fp32 accumulate.
// ---------------------------------------------------------------------------
__global__ __launch_bounds__(256, 4) void roi_align_nhwc(const _Float16* __restrict__ feat,
                                                         const float* __restrict__ rois,
                                                         float* __restrict__ out) {
    const int bid   = blockIdx.x;
    const int slice = bid & 7;
    const int r     = bid >> 3;
    const int c0    = slice * 32;
    const int tid   = threadIdx.x;
    const int cg    = tid & 7;         // channel group (4 channels)
    const int slot  = tid >> 3;        // bin slot 0..31

    __shared__ float tile[32 * NBINS];  // 6272 B

    const float* roi = rois + (size_t)r * 5;
    const int   b  = (int)roi[0];
    const float sx = roi[1] * SCALE - 0.5f;
    const float sy = roi[2] * SCALE - 0.5f;
    const float ex = roi[3] * SCALE - 0.5f;
    const float ey = roi[4] * SCALE - 0.5f;
    const float bin_h = (ey - sy) * (1.0f / (float)OUT_H);
    const float bin_w = (ex - sx) * (1.0f / (float)OUT_W);

    const _Float16* fb = feat + ((size_t)b * FS) * CCH + (c0 + cg * 4);

    for (int bin = slot; bin < NBINS; bin += 32) {
        const int ph = bin / 7;
        const int pw = bin - ph * 7;
        float ax = 0.f, ay = 0.f, az = 0.f, aw = 0.f;
#pragma unroll
        for (int iy = 0; iy < 2; ++iy) {
            float y = sy + ((float)ph + 0.25f + 0.5f * (float)iy) * bin_h;
            const bool vy = (y >= -1.0f) && (y <= (float)FH);
            y = fminf(fmaxf(y, 0.0f), (float)(FH - 1));
            const int ylo = (int)y;  // y >= 0, trunc == floor
            const int yhi = min(ylo + 1, FH - 1);
            const float ly = y - (float)ylo, hy = 1.0f - ly;
#pragma unroll
            for (int ix = 0; ix < 2; ++ix) {
                float x = sx + ((float)pw + 0.25f + 0.5f * (float)ix) * bin_w;
                const bool vx = (x >= -1.0f) && (x <= (float)FW);
                x = fminf(fmaxf(x, 0.0f), (float)(FW - 1));
                const int xlo = (int)x;
                const int xhi = min(xlo + 1, FW - 1);
                const float lx = x - (float)xlo, hx = 1.0f - lx;
                if (vy && vx) {
                    const half4 f00 = *(const half4*)&fb[(size_t)(ylo * FW + xlo) * CCH];
                    const half4 f01 = *(const half4*)&fb[(size_t)(ylo * FW + xhi) * CCH];
                    const half4 f10 = *(const half4*)&fb[(size_t)(yhi * FW + xlo) * CCH];
                    const half4 f11 = *(const half4*)&fb[(size_t)(yhi * FW + xhi) * CCH];
                    const float w00 = hy * hx, w01 = hy * lx, w10 = ly * hx, w11 = ly * lx;
                    ax += w00 * (float)f00.x + w01 * (float)f01.x + w10 * (float)f10.x + w11 * (float)f11.x;
                    ay += w00 * (float)f00.y + w01 * (float)f01.y + w10 * (float)f10.y + w11 * (float)f11.y;
                    az += w00 * (float)f00.z + w01 * (float)f01.z + w10 * (float)f10.z + w11 * (float)f11.z;
                    aw += w00 * (float)f00.w + w01 * (float)f01.w + w10 * (float)f10.w + w11 * (float)f11.w;
                }
            }
        }
        const int chb = cg * 4;
        tile[(chb + 0) * NBINS + bin] = ax * 0.25f;
        tile[(chb + 1) * NBINS + bin] = ay * 0.25f;
        tile[(chb + 2) * NBINS + bin] = az * 0.25f;
        tile[(chb + 3) * NBINS + bin] = aw * 0.25f;
    }

    __syncthreads();
    // Contiguous, coalesced write: 32*49 floats = 392 float4.
    float4* outr4 = (float4*)(out + ((size_t)r * CCH + c0) * NBINS);
    const float4* tile4 = (const float4*)tile;
    for (int i = tid; i < (32 * NBINS) / 4; i += 256) outr4[i] = tile4[i];
}

// ---------------------------------------------------------------------------
// Fallback: direct NCHW fp32 kernel (used only if workspace is too small).
// ---------------------------------------------------------------------------
__global__ __launch_bounds__(256) void roi_align_nchw(const float* __restrict__ feat,
                                                      const float* __restrict__ rois,
                                                      float* __restrict__ out) {
    const int r = blockIdx.x;
    const int c = threadIdx.x;
    __shared__ float tile[CCH * NBINS];

    const float* roi = rois + (size_t)r * 5;
    const int   b  = (int)roi[0];
    const float sx = roi[1] * SCALE - 0.5f;
    const float sy = roi[2] * SCALE - 0.5f;
    const float ex = roi[3] * SCALE - 0.5f;
    const float ey = roi[4] * SCALE - 0.5f;
    const float bin_h = (ey - sy) / (float)OUT_H;
    const float bin_w = (ex - sx) / (float)OUT_W;
    const float* fb = feat + ((size_t)b * CCH + c) * FS;

    for (int bin = 0; bin < NBINS; ++bin) {
        const int ph = bin / 7, pw = bin - ph * 7;
        float acc = 0.0f;
#pragma unroll
        for (int iy = 0; iy < 2; ++iy) {
#pragma unroll
            for (int ix = 0; ix < 2; ++ix) {
                float y = sy + ((float)ph + 0.25f + 0.5f * iy) * bin_h;
                float x = sx + ((float)pw + 0.25f + 0.5f * ix) * bin_w;
                bool valid = (y >= -1.0f) && (y <= (float)FH) && (x >= -1.0f) && (x <= (float)FW);
                y = fminf(fmaxf(y, 0.0f), (float)(FH - 1));
                x = fminf(fmaxf(x, 0.0f), (float)(FW - 1));
                int ylo = (int)y, xlo = (int)x;
                int yhi = min(ylo + 1, FH - 1), xhi = min(xlo + 1, FW - 1);
                float ly = y - ylo, lx = x - xlo, hy = 1.f - ly, hx = 1.f - lx;
                if (valid)
                    acc += hy * hx * fb[ylo * FW + xlo] + hy * lx * fb[ylo * FW + xhi] +
                           ly * hx * fb[yhi * FW + xlo] + ly * lx * fb[yhi * FW + xhi];
            }
        }
        tile[c * NBINS + bin] = acc * 0.25f;
    }
    __syncthreads();
    float* outr = out + (size_t)r * CCH * NBINS;
    for (int i = c; i < CCH * NBINS; i += 256) outr[i] = tile[i];
}

extern "C" void kernel_launch(void* const* d_in, const int* in_sizes, int n_in,
                              void* d_out, int out_size, void* d_ws, size_t ws_size,
                              hipStream_t stream) {
    const float* feat = (const float*)d_in[0];
    const float* rois = (const float*)d_in[1];
    float* out = (float*)d_out;

    const int R = in_sizes[1] / 5;
    const int N = in_sizes[0] / (CCH * FS);

    const size_t need = (size_t)N * FS * CCH * sizeof(_Float16);
    if (ws_size >= need) {
        dim3 tb(256);
        dim3 tg((FS + TS_S - 1) / TS_S, CCH / TS_C, N);
        transpose_kernel<<<tg, tb, 0, stream>>>(feat, (_Float16*)d_ws);
        roi_align_nhwc<<<R * 8, 256, 0, stream>>>((const _Float16*)d_ws, rois, out);
    } else {
        roi_align_nchw<<<R, 256, 0, stream>>>(feat, rois, out);
    }
}

// Round 6
// 30.490 us; speedup vs baseline: 3.1393x; 1.1337x over previous
//
#include <hip/hip_runtime.h>

// Problem constants (from reference)
#define OUT_H 7
#define OUT_W 7
#define NBINS 49
#define SCALE 0.0625f
#define CCH 256
#define FH 100
#define FW 100
#define FS (FH * FW)

typedef _Float16 half4 __attribute__((ext_vector_type(4)));
typedef _Float16 half8 __attribute__((ext_vector_type(8)));
typedef float f32x4 __attribute__((ext_vector_type(4)));

// ---------------------------------------------------------------------------
// Kernel 1: NCHW fp32 -> NHWC fp16 transpose.
// Tile: 32 channels x 128 spatial. float4 global reads, half4 global writes.
// ---------------------------------------------------------------------------
#define TS_S 128
#define TS_C 32

__global__ __launch_bounds__(256) void transpose_kernel(const float* __restrict__ in,
                                                        _Float16* __restrict__ out) {
    __shared__ float tile[TS_C][TS_S + 4];
    const int n  = blockIdx.z;
    const int s0 = blockIdx.x * TS_S;
    const int c0 = blockIdx.y * TS_C;
    const int tid = threadIdx.x;

    const int cr = tid >> 5;         // 0..7
    const int s4 = (tid & 31) * 4;   // 0..124
#pragma unroll
    for (int it = 0; it < 4; ++it) {
        const int c = c0 + cr + it * 8;
        const int s = s0 + s4;
        f32x4 v = {0.f, 0.f, 0.f, 0.f};
        if (s < FS) v = *(const f32x4*)&in[((size_t)n * CCH + c) * FS + s];
        *(f32x4*)&tile[cr + it * 8][s4] = v;
    }
    __syncthreads();
    const int c4  = (tid & 7) * 4;   // 0,4,..28
    const int sr0 = tid >> 3;        // 0..31
#pragma unroll
    for (int it = 0; it < 4; ++it) {
        const int sr = sr0 + it * 32;
        const int s  = s0 + sr;
        if (s < FS) {
            half4 v = { (_Float16)tile[c4 + 0][sr], (_Float16)tile[c4 + 1][sr],
                        (_Float16)tile[c4 + 2][sr], (_Float16)tile[c4 + 3][sr] };
            *(half4*)&out[((size_t)n * FS + s) * CCH + c0 + c4] = v;
        }
    }
}

// ---------------------------------------------------------------------------
// Kernel 2: RoIAlign on NHWC fp16.
// Grid = R*2 blocks (slice = 128 channels) of 256 threads = 8 waves.
// 1024 blocks = exactly 4 blocks/CU, fully co-resident; launch_bounds(256,8)
// caps VGPR at 64 -> 32 waves/CU (100% occupancy).
// Thread = (cg: 8 ch via half8 16B load) x (bin slot 0..15, 3-4 bins each).
// fp32 accumulate; LDS-staged contiguous output, nontemporal f32x4 stores.
// ---------------------------------------------------------------------------
#define SLICE_CH 128

__global__ __launch_bounds__(256, 8) void roi_align_nhwc(const _Float16* __restrict__ feat,
                                                         const float* __restrict__ rois,
                                                         float* __restrict__ out) {
    const int bid   = blockIdx.x;
    const int slice = bid & 1;
    const int r     = bid >> 1;
    const int tid   = threadIdx.x;
    const int cg    = tid & 15;        // 16 channel groups of 8 ch
    const int slot  = tid >> 4;        // bin slot 0..15

    __shared__ float tile[SLICE_CH * NBINS];  // 25088 B

    const float* roi = rois + (size_t)r * 5;
    const int   b  = (int)roi[0];
    const float sx = roi[1] * SCALE - 0.5f;
    const float sy = roi[2] * SCALE - 0.5f;
    const float ex = roi[3] * SCALE - 0.5f;
    const float ey = roi[4] * SCALE - 0.5f;
    const float bin_h = (ey - sy) * (1.0f / (float)OUT_H);
    const float bin_w = (ex - sx) * (1.0f / (float)OUT_W);

    const _Float16* fb = feat + ((size_t)b * FS) * CCH + (slice * SLICE_CH + cg * 8);

    for (int bin = slot; bin < NBINS; bin += 16) {
        const int ph = bin / 7;
        const int pw = bin - ph * 7;
        float a[8];
#pragma unroll
        for (int k = 0; k < 8; ++k) a[k] = 0.f;
#pragma unroll
        for (int iy = 0; iy < 2; ++iy) {
            float y = sy + ((float)ph + 0.25f + 0.5f * (float)iy) * bin_h;
            const bool vy = (y >= -1.0f) && (y <= (float)FH);
            y = fminf(fmaxf(y, 0.0f), (float)(FH - 1));
            const int ylo = (int)y;  // y >= 0, trunc == floor
            const int yhi = min(ylo + 1, FH - 1);
            const float ly = y - (float)ylo, hy = 1.0f - ly;
#pragma unroll
            for (int ix = 0; ix < 2; ++ix) {
                float x = sx + ((float)pw + 0.25f + 0.5f * (float)ix) * bin_w;
                const bool vx = (x >= -1.0f) && (x <= (float)FW);
                x = fminf(fmaxf(x, 0.0f), (float)(FW - 1));
                const int xlo = (int)x;
                const int xhi = min(xlo + 1, FW - 1);
                const float lx = x - (float)xlo, hx = 1.0f - lx;
                if (vy && vx) {
                    const half8 f00 = *(const half8*)&fb[(size_t)(ylo * FW + xlo) * CCH];
                    const half8 f01 = *(const half8*)&fb[(size_t)(ylo * FW + xhi) * CCH];
                    const half8 f10 = *(const half8*)&fb[(size_t)(yhi * FW + xlo) * CCH];
                    const half8 f11 = *(const half8*)&fb[(size_t)(yhi * FW + xhi) * CCH];
                    const float w00 = hy * hx, w01 = hy * lx, w10 = ly * hx, w11 = ly * lx;
#pragma unroll
                    for (int k = 0; k < 8; ++k)
                        a[k] += w00 * (float)f00[k] + w01 * (float)f01[k] +
                                w10 * (float)f10[k] + w11 * (float)f11[k];
                }
            }
        }
        const int chb = cg * 8;
#pragma unroll
        for (int k = 0; k < 8; ++k)
            tile[(chb + k) * NBINS + bin] = a[k] * 0.25f;
    }

    __syncthreads();
    // Contiguous coalesced write: 128*49 floats = 1568 f32x4, nontemporal.
    float* outr = out + ((size_t)r * CCH + slice * SLICE_CH) * NBINS;
    const f32x4* tile4 = (const f32x4*)tile;
    f32x4* outr4 = (f32x4*)outr;
    for (int i = tid; i < (SLICE_CH * NBINS) / 4; i += 256)
        __builtin_nontemporal_store(tile4[i], &outr4[i]);
}

// ---------------------------------------------------------------------------
// Fallback: direct NCHW fp32 kernel (used only if workspace is too small).
// ---------------------------------------------------------------------------
__global__ __launch_bounds__(256) void roi_align_nchw(const float* __restrict__ feat,
                                                      const float* __restrict__ rois,
                                                      float* __restrict__ out) {
    const int r = blockIdx.x;
    const int c = threadIdx.x;
    __shared__ float tile[CCH * NBINS];

    const float* roi = rois + (size_t)r * 5;
    const int   b  = (int)roi[0];
    const float sx = roi[1] * SCALE - 0.5f;
    const float sy = roi[2] * SCALE - 0.5f;
    const float ex = roi[3] * SCALE - 0.5f;
    const float ey = roi[4] * SCALE - 0.5f;
    const float bin_h = (ey - sy) / (float)OUT_H;
    const float bin_w = (ex - sx) / (float)OUT_W;
    const float* fb = feat + ((size_t)b * CCH + c) * FS;

    for (int bin = 0; bin < NBINS; ++bin) {
        const int ph = bin / 7, pw = bin - ph * 7;
        float acc = 0.0f;
#pragma unroll
        for (int iy = 0; iy < 2; ++iy) {
#pragma unroll
            for (int ix = 0; ix < 2; ++ix) {
                float y = sy + ((float)ph + 0.25f + 0.5f * iy) * bin_h;
                float x = sx + ((float)pw + 0.25f + 0.5f * ix) * bin_w;
                bool valid = (y >= -1.0f) && (y <= (float)FH) && (x >= -1.0f) && (x <= (float)FW);
                y = fminf(fmaxf(y, 0.0f), (float)(FH - 1));
                x = fminf(fmaxf(x, 0.0f), (float)(FW - 1));
                int ylo = (int)y, xlo = (int)x;
                int yhi = min(ylo + 1, FH - 1), xhi = min(xlo + 1, FW - 1);
                float ly = y - ylo, lx = x - xlo, hy = 1.f - ly, hx = 1.f - lx;
                if (valid)
                    acc += hy * hx * fb[ylo * FW + xlo] + hy * lx * fb[ylo * FW + xhi] +
                           ly * hx * fb[yhi * FW + xlo] + ly * lx * fb[yhi * FW + xhi];
            }
        }
        tile[c * NBINS + bin] = acc * 0.25f;
    }
    __syncthreads();
    float* outr = out + (size_t)r * CCH * NBINS;
    for (int i = c; i < CCH * NBINS; i += 256) outr[i] = tile[i];
}

extern "C" void kernel_launch(void* const* d_in, const int* in_sizes, int n_in,
                              void* d_out, int out_size, void* d_ws, size_t ws_size,
                              hipStream_t stream) {
    const float* feat = (const float*)d_in[0];
    const float* rois = (const float*)d_in[1];
    float* out = (float*)d_out;

    const int R = in_sizes[1] / 5;
    const int N = in_sizes[0] / (CCH * FS);

    const size_t need = (size_t)N * FS * CCH * sizeof(_Float16);
    if (ws_size >= need) {
        dim3 tb(256);
        dim3 tg((FS + TS_S - 1) / TS_S, CCH / TS_C, N);
        transpose_kernel<<<tg, tb, 0, stream>>>(feat, (_Float16*)d_ws);
        roi_align_nhwc<<<R * 2, 256, 0, stream>>>((const _Float16*)d_ws, rois, out);
    } else {
        roi_align_nchw<<<R, 256, 0, stream>>>(feat, rois, out);
    }
}

// Round 7
// 27.522 us; speedup vs baseline: 3.4778x; 1.1078x over previous
//
#include <hip/hip_runtime.h>

// Problem constants (from reference)
#define OUT_H 7
#define OUT_W 7
#define NBINS 49
#define SCALE 0.0625f
#define CCH 256
#define FH 100
#define FW 100
#define FS (FH * FW)

typedef _Float16 half4 __attribute__((ext_vector_type(4)));
typedef _Float16 half8 __attribute__((ext_vector_type(8)));
typedef float f32x4 __attribute__((ext_vector_type(4)));
typedef int   i32x4 __attribute__((ext_vector_type(4)));

// ---------------------------------------------------------------------------
// Kernel 1: NCHW fp32 -> NHWC fp16 transpose.
// Tile: 32 channels x 128 spatial. float4 global reads, half4 global writes.
// ---------------------------------------------------------------------------
#define TS_S 128
#define TS_C 32

__global__ __launch_bounds__(256) void transpose_kernel(const float* __restrict__ in,
                                                        _Float16* __restrict__ out) {
    __shared__ float tile[TS_C][TS_S + 4];
    const int n  = blockIdx.z;
    const int s0 = blockIdx.x * TS_S;
    const int c0 = blockIdx.y * TS_C;
    const int tid = threadIdx.x;

    const int cr = tid >> 5;         // 0..7
    const int s4 = (tid & 31) * 4;   // 0..124
#pragma unroll
    for (int it = 0; it < 4; ++it) {
        const int c = c0 + cr + it * 8;
        const int s = s0 + s4;
        f32x4 v = {0.f, 0.f, 0.f, 0.f};
        if (s < FS) v = *(const f32x4*)&in[((size_t)n * CCH + c) * FS + s];
        *(f32x4*)&tile[cr + it * 8][s4] = v;
    }
    __syncthreads();
    const int c4  = (tid & 7) * 4;   // 0,4,..28
    const int sr0 = tid >> 3;        // 0..31
#pragma unroll
    for (int it = 0; it < 4; ++it) {
        const int sr = sr0 + it * 32;
        const int s  = s0 + sr;
        if (s < FS) {
            half4 v = { (_Float16)tile[c4 + 0][sr], (_Float16)tile[c4 + 1][sr],
                        (_Float16)tile[c4 + 2][sr], (_Float16)tile[c4 + 3][sr] };
            *(half4*)&out[((size_t)n * FS + s) * CCH + c0 + c4] = v;
        }
    }
}

// ---------------------------------------------------------------------------
// Kernel 2: RoIAlign on NHWC fp16.
// Grid = R*2 blocks (slice = 128 channels), 256 threads = 8 waves,
// 1024 blocks = 4 blocks/CU fully co-resident.
// Phase 1 (196 threads): per (bin,sample) compute 4 corner offsets + 4
//   weights ONCE into LDS (invalid sample -> weights 0: no inner branch).
// Phase 2: thread = (cg: 8ch half8) x (bin slot 0..15). Inner loop is pure
//   LDS-broadcast reads + 16B global loads + mixed-precision FMA.
// Output staged in LDS -> contiguous nontemporal f32x4 stores.
// ---------------------------------------------------------------------------
#define SLICE_CH 128

__global__ __launch_bounds__(256, 8) void roi_align_nhwc(const _Float16* __restrict__ feat,
                                                         const float* __restrict__ rois,
                                                         float* __restrict__ out) {
    const int bid   = blockIdx.x;
    const int slice = bid & 1;
    const int r     = bid >> 1;
    const int tid   = threadIdx.x;
    const int cg    = tid & 15;        // 16 channel groups of 8 ch
    const int slot  = tid >> 4;        // bin slot 0..15

    __shared__ float tile[SLICE_CH * NBINS];  // 25088 B
    __shared__ i32x4 soff[NBINS * 4];         // 3136 B: 4 corner offsets/sample
    __shared__ f32x4 swt[NBINS * 4];          // 3136 B: 4 corner weights/sample

    const float* roi = rois + (size_t)r * 5;
    const int b = (int)roi[0];

    // ---- Phase 1: per-sample precompute (one sample per thread) ----
    if (tid < NBINS * 4) {
        const int bin = tid >> 2;
        const int s   = tid & 3;
        const int iy  = s >> 1;
        const int ix  = s & 1;
        const int ph  = bin / 7;
        const int pw  = bin - ph * 7;

        const float sx = roi[1] * SCALE - 0.5f;
        const float sy = roi[2] * SCALE - 0.5f;
        const float ex = roi[3] * SCALE - 0.5f;
        const float ey = roi[4] * SCALE - 0.5f;
        const float bin_h = (ey - sy) * (1.0f / (float)OUT_H);
        const float bin_w = (ex - sx) * (1.0f / (float)OUT_W);

        float y = sy + ((float)ph + 0.25f + 0.5f * (float)iy) * bin_h;
        float x = sx + ((float)pw + 0.25f + 0.5f * (float)ix) * bin_w;
        const bool valid = (y >= -1.0f) && (y <= (float)FH) &&
                           (x >= -1.0f) && (x <= (float)FW);
        y = fminf(fmaxf(y, 0.0f), (float)(FH - 1));
        x = fminf(fmaxf(x, 0.0f), (float)(FW - 1));
        const int ylo = (int)y;  // y >= 0, trunc == floor
        const int xlo = (int)x;
        const int yhi = min(ylo + 1, FH - 1);
        const int xhi = min(xlo + 1, FW - 1);
        const float ly = y - (float)ylo, lx = x - (float)xlo;
        const float hy = 1.0f - ly, hx = 1.0f - lx;
        const float vm = valid ? 1.0f : 0.0f;

        i32x4 o = { (ylo * FW + xlo) * CCH, (ylo * FW + xhi) * CCH,
                    (yhi * FW + xlo) * CCH, (yhi * FW + xhi) * CCH };
        f32x4 w = { vm * hy * hx, vm * hy * lx, vm * ly * hx, vm * ly * lx };
        soff[tid] = o;
        swt[tid]  = w;
    }
    __syncthreads();

    // ---- Phase 2: gather + accumulate ----
    const _Float16* fb = feat + ((size_t)b * FS) * CCH + (slice * SLICE_CH + cg * 8);

    for (int bin = slot; bin < NBINS; bin += 16) {
        float a[8];
#pragma unroll
        for (int k = 0; k < 8; ++k) a[k] = 0.f;
#pragma unroll
        for (int s = 0; s < 4; ++s) {
            const i32x4 o = soff[bin * 4 + s];  // broadcast ds_read_b128
            const f32x4 w = swt[bin * 4 + s];
            const half8 f00 = *(const half8*)&fb[o.x];
            const half8 f01 = *(const half8*)&fb[o.y];
            const half8 f10 = *(const half8*)&fb[o.z];
            const half8 f11 = *(const half8*)&fb[o.w];
#pragma unroll
            for (int k = 0; k < 8; ++k)
                a[k] += w.x * (float)f00[k] + w.y * (float)f01[k] +
                        w.z * (float)f10[k] + w.w * (float)f11[k];
        }
        const int chb = cg * 8;
#pragma unroll
        for (int k = 0; k < 8; ++k)
            tile[(chb + k) * NBINS + bin] = a[k] * 0.25f;
    }

    __syncthreads();
    // Contiguous coalesced write: 128*49 floats = 1568 f32x4, nontemporal.
    float* outr = out + ((size_t)r * CCH + slice * SLICE_CH) * NBINS;
    const f32x4* tile4 = (const f32x4*)tile;
    f32x4* outr4 = (f32x4*)outr;
    for (int i = tid; i < (SLICE_CH * NBINS) / 4; i += 256)
        __builtin_nontemporal_store(tile4[i], &outr4[i]);
}

// ---------------------------------------------------------------------------
// Fallback: direct NCHW fp32 kernel (used only if workspace is too small).
// ---------------------------------------------------------------------------
__global__ __launch_bounds__(256) void roi_align_nchw(const float* __restrict__ feat,
                                                      const float* __restrict__ rois,
                                                      float* __restrict__ out) {
    const int r = blockIdx.x;
    const int c = threadIdx.x;
    __shared__ float tile[CCH * NBINS];

    const float* roi = rois + (size_t)r * 5;
    const int   b  = (int)roi[0];
    const float sx = roi[1] * SCALE - 0.5f;
    const float sy = roi[2] * SCALE - 0.5f;
    const float ex = roi[3] * SCALE - 0.5f;
    const float ey = roi[4] * SCALE - 0.5f;
    const float bin_h = (ey - sy) / (float)OUT_H;
    const float bin_w = (ex - sx) / (float)OUT_W;
    const float* fb = feat + ((size_t)b * CCH + c) * FS;

    for (int bin = 0; bin < NBINS; ++bin) {
        const int ph = bin / 7, pw = bin - ph * 7;
        float acc = 0.0f;
#pragma unroll
        for (int iy = 0; iy < 2; ++iy) {
#pragma unroll
            for (int ix = 0; ix < 2; ++ix) {
                float y = sy + ((float)ph + 0.25f + 0.5f * iy) * bin_h;
                float x = sx + ((float)pw + 0.25f + 0.5f * ix) * bin_w;
                bool valid = (y >= -1.0f) && (y <= (float)FH) && (x >= -1.0f) && (x <= (float)FW);
                y = fminf(fmaxf(y, 0.0f), (float)(FH - 1));
                x = fminf(fmaxf(x, 0.0f), (float)(FW - 1));
                int ylo = (int)y, xlo = (int)x;
                int yhi = min(ylo + 1, FH - 1), xhi = min(xlo + 1, FW - 1);
                float ly = y - ylo, lx = x - xlo, hy = 1.f - ly, hx = 1.f - lx;
                if (valid)
                    acc += hy * hx * fb[ylo * FW + xlo] + hy * lx * fb[ylo * FW + xhi] +
                           ly * hx * fb[yhi * FW + xlo] + ly * lx * fb[yhi * FW + xhi];
            }
        }
        tile[c * NBINS + bin] = acc * 0.25f;
    }
    __syncthreads();
    float* outr = out + (size_t)r * CCH * NBINS;
    for (int i = c; i < CCH * NBINS; i += 256) outr[i] = tile[i];
}

extern "C" void kernel_launch(void* const* d_in, const int* in_sizes, int n_in,
                              void* d_out, int out_size, void* d_ws, size_t ws_size,
                              hipStream_t stream) {
    const float* feat = (const float*)d_in[0];
    const float* rois = (const float*)d_in[1];
    float* out = (float*)d_out;

    const int R = in_sizes[1] / 5;
    const int N = in_sizes[0] / (CCH * FS);

    const size_t need = (size_t)N * FS * CCH * sizeof(_Float16);
    if (ws_size >= need) {
        dim3 tb(256);
        dim3 tg((FS + TS_S - 1) / TS_S, CCH / TS_C, N);
        transpose_kernel<<<tg, tb, 0, stream>>>(feat, (_Float16*)d_ws);
        roi_align_nhwc<<<R * 2, 256, 0, stream>>>((const _Float16*)d_ws, rois, out);
    } else {
        roi_align_nchw<<<R, 256, 0, stream>>>(feat, rois, out);
    }
}

// Round 8
// 27.059 us; speedup vs baseline: 3.5374x; 1.0171x over previous
//
#include <hip/hip_runtime.h>

// Problem constants (from reference)
#define OUT_H 7
#define OUT_W 7
#define NBINS 49
#define SCALE 0.0625f
#define CCH 256
#define FH 100
#define FW 100
#define FS (FH * FW)

typedef _Float16 half4 __attribute__((ext_vector_type(4)));
typedef _Float16 half8 __attribute__((ext_vector_type(8)));
typedef float f32x4 __attribute__((ext_vector_type(4)));
typedef int   i32x4 __attribute__((ext_vector_type(4)));

// ---------------------------------------------------------------------------
// Kernel 1: NCHW fp32 -> NHWC fp16 transpose.
// ---------------------------------------------------------------------------
#define TS_S 128
#define TS_C 32

__global__ __launch_bounds__(256) void transpose_kernel(const float* __restrict__ in,
                                                        _Float16* __restrict__ out) {
    __shared__ float tile[TS_C][TS_S + 4];
    const int n  = blockIdx.z;
    const int s0 = blockIdx.x * TS_S;
    const int c0 = blockIdx.y * TS_C;
    const int tid = threadIdx.x;

    const int cr = tid >> 5;         // 0..7
    const int s4 = (tid & 31) * 4;   // 0..124
#pragma unroll
    for (int it = 0; it < 4; ++it) {
        const int c = c0 + cr + it * 8;
        const int s = s0 + s4;
        f32x4 v = {0.f, 0.f, 0.f, 0.f};
        if (s < FS) v = *(const f32x4*)&in[((size_t)n * CCH + c) * FS + s];
        *(f32x4*)&tile[cr + it * 8][s4] = v;
    }
    __syncthreads();
    const int c4  = (tid & 7) * 4;   // 0,4,..28
    const int sr0 = tid >> 3;        // 0..31
#pragma unroll
    for (int it = 0; it < 4; ++it) {
        const int sr = sr0 + it * 32;
        const int s  = s0 + sr;
        if (s < FS) {
            half4 v = { (_Float16)tile[c4 + 0][sr], (_Float16)tile[c4 + 1][sr],
                        (_Float16)tile[c4 + 2][sr], (_Float16)tile[c4 + 3][sr] };
            *(half4*)&out[((size_t)n * FS + s) * CCH + c0 + c4] = v;
        }
    }
}

// ---------------------------------------------------------------------------
// Kernel 2: RoIAlign on NHWC fp16.
// Grid = R*2 blocks (slice = 128 channels), 256 threads = 8 waves.
// launch_bounds(256,4): 128 VGPR so all 16 half8 loads of a bin are in
// flight simultaneously (one latency exposure per bin). LDS 29.8KB -> still
// 4 blocks/CU co-resident.
// Phase 1: per (bin,sample) corner offsets + fp16 weights (pre-scaled 0.25,
// invalid -> 0) once into LDS.
// Phase 2: packed fp16 accumulate (v_pk_fma_f16), fp32 only at epilogue.
// ---------------------------------------------------------------------------
#define SLICE_CH 128

__global__ __launch_bounds__(256, 4) void roi_align_nhwc(const _Float16* __restrict__ feat,
                                                         const float* __restrict__ rois,
                                                         float* __restrict__ out) {
    const int bid   = blockIdx.x;
    const int slice = bid & 1;
    const int r     = bid >> 1;
    const int tid   = threadIdx.x;
    const int cg    = tid & 15;        // 16 channel groups of 8 ch
    const int slot  = tid >> 4;        // bin slot 0..15

    __shared__ float tile[SLICE_CH * NBINS];  // 25088 B
    __shared__ i32x4 soff[NBINS * 4];         // 3136 B
    __shared__ half4 swt[NBINS * 4];          // 1568 B

    const float* roi = rois + (size_t)r * 5;
    const int b = (int)roi[0];

    // ---- Phase 1: per-sample precompute (one sample per thread) ----
    if (tid < NBINS * 4) {
        const int bin = tid >> 2;
        const int s   = tid & 3;
        const int iy  = s >> 1;
        const int ix  = s & 1;
        const int ph  = bin / 7;
        const int pw  = bin - ph * 7;

        const float sx = roi[1] * SCALE - 0.5f;
        const float sy = roi[2] * SCALE - 0.5f;
        const float ex = roi[3] * SCALE - 0.5f;
        const float ey = roi[4] * SCALE - 0.5f;
        const float bin_h = (ey - sy) * (1.0f / (float)OUT_H);
        const float bin_w = (ex - sx) * (1.0f / (float)OUT_W);

        float y = sy + ((float)ph + 0.25f + 0.5f * (float)iy) * bin_h;
        float x = sx + ((float)pw + 0.25f + 0.5f * (float)ix) * bin_w;
        const bool valid = (y >= -1.0f) && (y <= (float)FH) &&
                           (x >= -1.0f) && (x <= (float)FW);
        y = fminf(fmaxf(y, 0.0f), (float)(FH - 1));
        x = fminf(fmaxf(x, 0.0f), (float)(FW - 1));
        const int ylo = (int)y;  // y >= 0, trunc == floor
        const int xlo = (int)x;
        const int yhi = min(ylo + 1, FH - 1);
        const int xhi = min(xlo + 1, FW - 1);
        const float ly = y - (float)ylo, lx = x - (float)xlo;
        const float hy = 1.0f - ly, hx = 1.0f - lx;
        const float vm = valid ? 0.25f : 0.0f;  // fold the /4 into the weights

        i32x4 o = { (ylo * FW + xlo) * CCH, (ylo * FW + xhi) * CCH,
                    (yhi * FW + xlo) * CCH, (yhi * FW + xhi) * CCH };
        half4 w = { (_Float16)(vm * hy * hx), (_Float16)(vm * hy * lx),
                    (_Float16)(vm * ly * hx), (_Float16)(vm * ly * lx) };
        soff[tid] = o;
        swt[tid]  = w;
    }
    __syncthreads();

    // ---- Phase 2: gather + packed fp16 accumulate ----
    const _Float16* fb = feat + ((size_t)b * FS) * CCH + (slice * SLICE_CH + cg * 8);

    for (int bin = slot; bin < NBINS; bin += 16) {
        half8 acc = {0, 0, 0, 0, 0, 0, 0, 0};
#pragma unroll
        for (int s = 0; s < 4; ++s) {
            const i32x4 o = soff[bin * 4 + s];  // broadcast ds_read_b128
            const half4 w = swt[bin * 4 + s];
            const half8 f00 = *(const half8*)&fb[o.x];
            const half8 f01 = *(const half8*)&fb[o.y];
            const half8 f10 = *(const half8*)&fb[o.z];
            const half8 f11 = *(const half8*)&fb[o.w];
            acc += f00 * w.x;   // v_pk_fma_f16 x4
            acc += f01 * w.y;
            acc += f10 * w.z;
            acc += f11 * w.w;
        }
        const int chb = cg * 8;
#pragma unroll
        for (int k = 0; k < 8; ++k)
            tile[(chb + k) * NBINS + bin] = (float)acc[k];
    }

    __syncthreads();
    // Contiguous coalesced write: 128*49 floats = 1568 f32x4, nontemporal.
    float* outr = out + ((size_t)r * CCH + slice * SLICE_CH) * NBINS;
    const f32x4* tile4 = (const f32x4*)tile;
    f32x4* outr4 = (f32x4*)outr;
    for (int i = tid; i < (SLICE_CH * NBINS) / 4; i += 256)
        __builtin_nontemporal_store(tile4[i], &outr4[i]);
}

// ---------------------------------------------------------------------------
// Fallback: direct NCHW fp32 kernel (used only if workspace is too small).
// ---------------------------------------------------------------------------
__global__ __launch_bounds__(256) void roi_align_nchw(const float* __restrict__ feat,
                                                      const float* __restrict__ rois,
                                                      float* __restrict__ out) {
    const int r = blockIdx.x;
    const int c = threadIdx.x;
    __shared__ float tile[CCH * NBINS];

    const float* roi = rois + (size_t)r * 5;
    const int   b  = (int)roi[0];
    const float sx = roi[1] * SCALE - 0.5f;
    const float sy = roi[2] * SCALE - 0.5f;
    const float ex = roi[3] * SCALE - 0.5f;
    const float ey = roi[4] * SCALE - 0.5f;
    const float bin_h = (ey - sy) / (float)OUT_H;
    const float bin_w = (ex - sx) / (float)OUT_W;
    const float* fb = feat + ((size_t)b * CCH + c) * FS;

    for (int bin = 0; bin < NBINS; ++bin) {
        const int ph = bin / 7, pw = bin - ph * 7;
        float acc = 0.0f;
#pragma unroll
        for (int iy = 0; iy < 2; ++iy) {
#pragma unroll
            for (int ix = 0; ix < 2; ++ix) {
                float y = sy + ((float)ph + 0.25f + 0.5f * iy) * bin_h;
                float x = sx + ((float)pw + 0.25f + 0.5f * ix) * bin_w;
                bool valid = (y >= -1.0f) && (y <= (float)FH) && (x >= -1.0f) && (x <= (float)FW);
                y = fminf(fmaxf(y, 0.0f), (float)(FH - 1));
                x = fminf(fmaxf(x, 0.0f), (float)(FW - 1));
                int ylo = (int)y, xlo = (int)x;
                int yhi = min(ylo + 1, FH - 1), xhi = min(xlo + 1, FW - 1);
                float ly = y - ylo, lx = x - xlo, hy = 1.f - ly, hx = 1.f - lx;
                if (valid)
                    acc += hy * hx * fb[ylo * FW + xlo] + hy * lx * fb[ylo * FW + xhi] +
                           ly * hx * fb[yhi * FW + xlo] + ly * lx * fb[yhi * FW + xhi];
            }
        }
        tile[c * NBINS + bin] = acc * 0.25f;
    }
    __syncthreads();
    float* outr = out + (size_t)r * CCH * NBINS;
    for (int i = c; i < CCH * NBINS; i += 256) outr[i] = tile[i];
}

extern "C" void kernel_launch(void* const* d_in, const int* in_sizes, int n_in,
                              void* d_out, int out_size, void* d_ws, size_t ws_size,
                              hipStream_t stream) {
    const float* feat = (const float*)d_in[0];
    const float* rois = (const float*)d_in[1];
    float* out = (float*)d_out;

    const int R = in_sizes[1] / 5;
    const int N = in_sizes[0] / (CCH * FS);

    const size_t need = (size_t)N * FS * CCH * sizeof(_Float16);
    if (ws_size >= need) {
        dim3 tb(256);
        dim3 tg((FS + TS_S - 1) / TS_S, CCH / TS_C, N);
        transpose_kernel<<<tg, tb, 0, stream>>>(feat, (_Float16*)d_ws);
        roi_align_nhwc<<<R * 2, 256, 0, stream>>>((const _Float16*)d_ws, rois, out);
    } else {
        roi_align_nchw<<<R, 256, 0, stream>>>(feat, rois, out);
    }
}